// Round 2
// baseline (2004.408 us; speedup 1.0000x reference)
//
#include <hip/hip_runtime.h>
#include <hip/hip_fp16.h>

#define DD 8
#define HH 256
#define CH 4096          // edges per chunk
#define PAYBITS 17       // N <= 131072
#define PAYMASK 0x1FFFF
#define WPITCH 20        // LDS weight row pitch (floats): conflict-free
#define NBLK 768         // 3 blocks/CU x 256 CUs -- guaranteed by launch_bounds(256,3)

// Fused persistent kernel, hand-rolled grid barrier with explicit agent-scope
// fences (buffer_wbl2/buffer_inv via __builtin_amdgcn_fence) -- the per-XCD
// L2s on gfx950 are non-coherent, so plain-store producer->consumer across
// blocks REQUIRES the release (L2 writeback) / acquire (L2 inv) pair around
// the barrier. Round-1's cg::grid.sync() path raced; this makes the fences
// explicit and drops cooperative launch entirely (regular launch, grid=768
// co-resident by construction).

struct Params {
    const float *q, *p, *M, *W1, *b1w, *W2, *b2w, *grav;
    const int *src, *dst;
    float *out;
    float *a, *bn, *qn, *agg1, *gh, *W12p;
    __half2 *hm;
    __half *ya, *bgh, *gz1b;
    float *gq2;                 // alias of qn
    int *csr_in, *csr_out, *start_in, *start_out;
    int *gHistIn, *gHistOut, *cStartIn, *cStartOut, *cCurIn, *cCurOut;
    int *P_in, *P_out;
    int *bar;                   // [0]=counter, [1]=sense flag (memset to 0)
    int N, E, NB, NC;
};

// ---------------- grid barrier (sense-reversing, agent-scope) ---------------
static __device__ __forceinline__
void gsync(int* __restrict__ bar, int& sense) {
    __syncthreads();                              // all block stores drained (waitcnt)
    if (threadIdx.x == 0) {
        __builtin_amdgcn_fence(__ATOMIC_RELEASE, "agent");   // wbl2: flush this XCD's L2
        int s = sense ^ 1;
        if (__hip_atomic_fetch_add(&bar[0], 1, __ATOMIC_ACQ_REL,
                                   __HIP_MEMORY_SCOPE_AGENT) == NBLK - 1) {
            __hip_atomic_store(&bar[0], 0, __ATOMIC_RELAXED, __HIP_MEMORY_SCOPE_AGENT);
            __hip_atomic_store(&bar[1], s, __ATOMIC_RELEASE, __HIP_MEMORY_SCOPE_AGENT);
        } else {
            while (__hip_atomic_load(&bar[1], __ATOMIC_RELAXED,
                                     __HIP_MEMORY_SCOPE_AGENT) != s)
                __builtin_amdgcn_s_sleep(2);
        }
        __builtin_amdgcn_fence(__ATOMIC_ACQUIRE, "agent");   // inv: no stale L1/L2 lines
    }
    sense ^= 1;
    __syncthreads();
}

// ------------------- record unpack/accumulate helpers -----------------------
static __device__ __forceinline__
void acc_h8(uint4 r, float acc[8]) {
    float2 f;
    f = __half22float2(*(__half2*)&r.x); acc[0] += f.x; acc[1] += f.y;
    f = __half22float2(*(__half2*)&r.y); acc[2] += f.x; acc[3] += f.y;
    f = __half22float2(*(__half2*)&r.z); acc[4] += f.x; acc[5] += f.y;
    f = __half22float2(*(__half2*)&r.w); acc[6] += f.x; acc[7] += f.y;
}

static __device__ __forceinline__
void unpack_hm(uint4 r0, uint4 r1, float h[8], float m[8]) {
    float2 f;
    f = __half22float2(*(__half2*)&r0.x); h[0] = f.x; m[0] = f.y;
    f = __half22float2(*(__half2*)&r0.y); h[1] = f.x; m[1] = f.y;
    f = __half22float2(*(__half2*)&r0.z); h[2] = f.x; m[2] = f.y;
    f = __half22float2(*(__half2*)&r0.w); h[3] = f.x; m[3] = f.y;
    f = __half22float2(*(__half2*)&r1.x); h[4] = f.x; m[4] = f.y;
    f = __half22float2(*(__half2*)&r1.y); h[5] = f.x; m[5] = f.y;
    f = __half22float2(*(__half2*)&r1.z); h[6] = f.x; m[6] = f.y;
    f = __half22float2(*(__half2*)&r1.w); h[7] = f.x; m[7] = f.y;
}

static __device__ __forceinline__
void gather_h8(const int* __restrict__ csr, const __half* __restrict__ x,
               int e, int e1, float acc[8]) {
    for (; e + 3 < e1; e += 4) {
        int u0 = csr[e], u1 = csr[e + 1], u2 = csr[e + 2], u3 = csr[e + 3];
        uint4 r0 = *(const uint4*)(x + (size_t)u0 * DD);
        uint4 r1 = *(const uint4*)(x + (size_t)u1 * DD);
        uint4 r2 = *(const uint4*)(x + (size_t)u2 * DD);
        uint4 r3 = *(const uint4*)(x + (size_t)u3 * DD);
        acc_h8(r0, acc); acc_h8(r1, acc); acc_h8(r2, acc); acc_h8(r3, acc);
    }
    for (; e < e1; e++) {
        uint4 r = *(const uint4*)(x + (size_t)csr[e] * DD);
        acc_h8(r, acc);
    }
}

// ============================ the mega kernel ===============================

__launch_bounds__(256, 3)
__global__ void mega(Params P) {
    __shared__ __align__(16) float smf[HH * WPITCH + HH];   // 21.5 KB, aliased
    int* smi = (int*)smf;
    const int tid  = threadIdx.x;
    const int gtid = blockIdx.x * 256 + tid;
    const int gstr = gridDim.x * 256;
    int sense = 0;

    // ---- prologue (no cross-block deps): weight pack + start[N]=E ----
    if (gtid == 0) { P.start_in[P.N] = P.E; P.start_out[P.N] = P.E; }
    for (int t = gtid; t < HH * DD; t += gstr) {
        int j = t >> 3, dd = t & 7;
        P.W12p[j * WPITCH + dd]     = P.W1[dd * HH + j];
        P.W12p[j * WPITCH + 8 + dd] = P.W2[j * DD + dd];
    }

    // ---- phase B: coarse per-chunk histograms (gHist zeroed by memset) ----
    for (int ch = blockIdx.x; ch < P.NC; ch += gridDim.x) {
        int* hIn = smi; int* hOut = smi + 256;
        hIn[tid] = 0; hOut[tid] = 0;
        __syncthreads();
        int lo = ch * CH, hi = min(lo + CH, P.E);
        for (int i = lo + tid; i < hi; i += 256) {
            atomicAdd(&hIn[P.dst[i] >> 9], 1);
            atomicAdd(&hOut[P.src[i] >> 9], 1);
        }
        __syncthreads();
        if (tid < P.NB) {
            int ci = hIn[tid], co = hOut[tid];
            if (ci) atomicAdd(&P.gHistIn[tid], ci);
            if (co) atomicAdd(&P.gHistOut[tid], co);
        }
        __syncthreads();
    }
    gsync(P.bar, sense);

    // ---- phase C: chunk-level exclusive scan (block 0 only) ----
    if (blockIdx.x == 0) {
#pragma unroll
        for (int dir = 0; dir < 2; dir++) {
            const int* gh_ = dir ? P.gHistOut : P.gHistIn;
            int* cs = dir ? P.cStartOut : P.cStartIn;
            int* cc = dir ? P.cCurOut : P.cCurIn;
            int v = (tid < P.NB) ? gh_[tid] : 0;
            smi[tid] = v;
            __syncthreads();
            for (int off = 1; off < 256; off <<= 1) {
                int t = (tid >= off) ? smi[tid - off] : 0;
                __syncthreads();
                smi[tid] += t;
                __syncthreads();
            }
            if (tid < P.NB) { int ex = smi[tid] - v; cs[tid] = ex; cc[tid] = ex; }
            if (tid == 0) cs[P.NB] = P.E;
            __syncthreads();
        }
    }
    gsync(P.bar, sense);

    // ---- phase D: partition into per-(chunk, 512-node-bin) runs ----
    for (int vb = blockIdx.x; vb < 2 * P.NC; vb += gridDim.x) {
        int dir = vb >= P.NC;
        int ch  = dir ? vb - P.NC : vb;
        const int* key = dir ? P.src : P.dst;
        const int* pay = dir ? P.dst : P.src;
        int* cCur = dir ? P.cCurOut : P.cCurIn;
        int* Pp   = dir ? P.P_out   : P.P_in;
        int* h = smi;
        h[tid] = 0;
        __syncthreads();
        int lo = ch * CH, hi = min(lo + CH, P.E);
        for (int i = lo + tid; i < hi; i += 256)
            atomicAdd(&h[key[i] >> 9], 1);
        __syncthreads();
        if (tid < P.NB) {
            int c = h[tid];
            h[tid] = c ? atomicAdd(&cCur[tid], c) : 0;
        }
        __syncthreads();
        for (int i = lo + tid; i < hi; i += 256) {
            int k = key[i];
            int pos = atomicAdd(&h[k >> 9], 1);
            Pp[pos] = ((k & 511) << PAYBITS) | pay[i];
        }
        __syncthreads();
    }
    gsync(P.bar, sense);

    // ---- phase E: fine sort within 512-node bins -> CSR ----
    for (int vb = blockIdx.x; vb < 2 * P.NB; vb += gridDim.x) {
        int dir = vb >= P.NB;
        int b   = dir ? vb - P.NB : vb;
        const int* cStart = dir ? P.cStartOut : P.cStartIn;
        const int* Pp     = dir ? P.P_out     : P.P_in;
        int* start        = dir ? P.start_out : P.start_in;
        int* csr          = dir ? P.csr_out   : P.csr_in;
        int* cnt = smi;              // 512
        int* scn = smi + 512;        // 512
        int* ps  = smi + 1024;       // 256
        int lo = cStart[b], hi = cStart[b + 1];
        cnt[tid] = 0; cnt[tid + 256] = 0;
        __syncthreads();
        for (int i = lo + tid; i < hi; i += 256)
            atomicAdd(&cnt[Pp[i] >> PAYBITS], 1);
        __syncthreads();
        int c0 = cnt[2 * tid], c1 = cnt[2 * tid + 1];
        int pair = c0 + c1;
        ps[tid] = pair;
        __syncthreads();
        for (int off = 1; off < 256; off <<= 1) {
            int t = (tid >= off) ? ps[tid - off] : 0;
            __syncthreads();
            ps[tid] += t;
            __syncthreads();
        }
        int excl = ps[tid] - pair;
        scn[2 * tid] = excl;
        scn[2 * tid + 1] = excl + c0;
        __syncthreads();
#pragma unroll
        for (int k = 0; k < 2; k++) {
            int i = tid + k * 256;
            int base = lo + scn[i];
            int node = (b << 9) + i;
            if (node < P.N) start[node] = base;
            cnt[i] = base;           // reuse as cursor
        }
        __syncthreads();
        for (int i = lo + tid; i < hi; i += 256) {
            int pv = Pp[i];
            int pos = atomicAdd(&cnt[pv >> PAYBITS], 1);
            csr[pos] = pv & PAYMASK;
        }
        __syncthreads();
    }
    gsync(P.bar, sense);

    // ---- phase F: per-node prep (norms, masses, dHdP) ----
    for (int v = gtid; v < P.N; v += gstr) {
        int ei1 = (v + 1 < P.N) ? P.start_in[v + 1]  : P.E;
        int eo1 = (v + 1 < P.N) ? P.start_out[v + 1] : P.E;
        float din  = (float)(ei1 - P.start_in[v]);
        float dout = (float)(eo1 - P.start_out[v]);
        float av = 1.0f / sqrtf(dout > 0.f ? dout : 1.f);
        float bv = 1.0f / sqrtf(din  > 0.f ? din  : 1.f);
        P.a[v] = av; P.bn[v] = bv;
#pragma unroll
        for (int d = 0; d < DD; d++) {
            float m = P.M[(size_t)v * DD * DD + d * (DD + 1)];
            __half2 hmv;
            hmv.x = __float2half(0.f);
            hmv.y = __float2half(m);
            P.hm[(size_t)v * DD + d] = hmv;
            P.qn[(size_t)v * DD + d] = av * P.q[(size_t)v * DD + d];
            P.out[(size_t)v * 2 * DD + DD + d] = P.p[(size_t)v * DD + d] / m;
        }
    }
    gsync(P.bar, sense);

    // ---- phase G: agg1 = AggIn(a*q), 2 thr/node ----
    for (int t = gtid; t < 2 * P.N; t += gstr) {
        int v = t >> 1, half = t & 1;
        int e0 = P.start_in[v], e1 = P.start_in[v + 1];
        int mid = e0 + ((e1 - e0) >> 1);
        int e = half ? mid : e0, hiE = half ? e1 : mid;
        float acc[8] = {0.f, 0.f, 0.f, 0.f, 0.f, 0.f, 0.f, 0.f};
        for (; e + 1 < hiE; e += 2) {
            int u0 = P.csr_in[e], u1 = P.csr_in[e + 1];
            const float4* p0 = (const float4*)(P.qn + (size_t)u0 * DD);
            const float4* p1 = (const float4*)(P.qn + (size_t)u1 * DD);
            float4 a0 = p0[0], b0 = p0[1], a1 = p1[0], b1 = p1[1];
            acc[0] += a0.x + a1.x; acc[1] += a0.y + a1.y;
            acc[2] += a0.z + a1.z; acc[3] += a0.w + a1.w;
            acc[4] += b0.x + b1.x; acc[5] += b0.y + b1.y;
            acc[6] += b0.z + b1.z; acc[7] += b0.w + b1.w;
        }
        if (e < hiE) {
            const float4* pp = (const float4*)(P.qn + (size_t)P.csr_in[e] * DD);
            float4 a0 = pp[0], b0 = pp[1];
            acc[0] += a0.x; acc[1] += a0.y; acc[2] += a0.z; acc[3] += a0.w;
            acc[4] += b0.x; acc[5] += b0.y; acc[6] += b0.z; acc[7] += b0.w;
        }
#pragma unroll
        for (int k = 0; k < 8; k++) acc[k] += __shfl_xor(acc[k], 1);
        if (!half) {
            float4* yp = (float4*)(P.agg1 + (size_t)v * DD);
            yp[0] = make_float4(acc[0], acc[1], acc[2], acc[3]);
            yp[1] = make_float4(acc[4], acc[5], acc[6], acc[7]);
        }
    }
    gsync(P.bar, sense);

    // ---- phase H: MLP forward, 16 lanes/node; weights -> LDS once/block ----
    float* sW  = smf;
    float* sb1 = smf + HH * WPITCH;
    for (int i = tid; i < HH * WPITCH; i += 256) sW[i] = P.W12p[i];
    for (int i = tid; i < HH; i += 256) sb1[i] = P.b1w[i];
    __syncthreads();
    for (int t = gtid; t < 16 * P.N; t += gstr) {
        int v = t >> 4, l16 = t & 15, sub = (t >> 3) & 1, d = t & 7;
        float zl = P.bn[v] * P.agg1[(size_t)v * DD + d];
        float z[DD];
#pragma unroll
        for (int k = 0; k < DD; k++) z[k] = __shfl(zl, k, 16);
        float acc[DD] = {0.f, 0.f, 0.f, 0.f, 0.f, 0.f, 0.f, 0.f};
        for (int c = 0; c < HH / 16; c += 2) {
            int j0 = (c << 4) | l16, j1 = j0 + 16;
            const float4* w0 = (const float4*)(sW + j0 * WPITCH);
            const float4* w1 = (const float4*)(sW + j1 * WPITCH);
            float4 wa0 = w0[0], wb0 = w0[1], va0 = w0[2], vb0 = w0[3];
            float4 wa1 = w1[0], wb1 = w1[1], va1 = w1[2], vb1 = w1[3];
            float ua0 = fmaf(z[1], wa0.y, fmaf(z[0], wa0.x, sb1[j0]));
            ua0 = fmaf(z[3], wa0.w, fmaf(z[2], wa0.z, ua0));
            float ub0 = fmaf(z[5], wb0.y, z[4] * wb0.x);
            ub0 = fmaf(z[7], wb0.w, fmaf(z[6], wb0.z, ub0));
            float ua1 = fmaf(z[1], wa1.y, fmaf(z[0], wa1.x, sb1[j1]));
            ua1 = fmaf(z[3], wa1.w, fmaf(z[2], wa1.z, ua1));
            float ub1 = fmaf(z[5], wb1.y, z[4] * wb1.x);
            ub1 = fmaf(z[7], wb1.w, fmaf(z[6], wb1.z, ub1));
            float h0 = fmaxf(ua0 + ub0, 0.f);
            float h1 = fmaxf(ua1 + ub1, 0.f);
            acc[0] = fmaf(h0, va0.x, acc[0]); acc[1] = fmaf(h0, va0.y, acc[1]);
            acc[2] = fmaf(h0, va0.z, acc[2]); acc[3] = fmaf(h0, va0.w, acc[3]);
            acc[4] = fmaf(h0, vb0.x, acc[4]); acc[5] = fmaf(h0, vb0.y, acc[5]);
            acc[6] = fmaf(h0, vb0.z, acc[6]); acc[7] = fmaf(h0, vb0.w, acc[7]);
            acc[0] = fmaf(h1, va1.x, acc[0]); acc[1] = fmaf(h1, va1.y, acc[1]);
            acc[2] = fmaf(h1, va1.z, acc[2]); acc[3] = fmaf(h1, va1.w, acc[3]);
            acc[4] = fmaf(h1, vb1.x, acc[4]); acc[5] = fmaf(h1, vb1.y, acc[5]);
            acc[6] = fmaf(h1, vb1.z, acc[6]); acc[7] = fmaf(h1, vb1.w, acc[7]);
        }
#pragma unroll
        for (int m = 1; m < 16; m <<= 1)
#pragma unroll
            for (int k = 0; k < DD; k++) acc[k] += __shfl_xor(acc[k], m);
        float yl = acc[0];
#pragma unroll
        for (int k = 1; k < DD; k++) yl = (d == k) ? acc[k] : yl;
        if (!sub) P.ya[(size_t)v * DD + d] = __float2half(P.a[v] * yl);
    }
    gsync(P.bar, sense);

    // ---- phase I: h = b*AggIn(ya) + b2 + q -> .x halves of hm ----
    for (int t = gtid; t < 2 * P.N; t += gstr) {
        int v = t >> 1, half = t & 1;
        int e0 = P.start_in[v], e1 = P.start_in[v + 1];
        int mid = e0 + ((e1 - e0) >> 1);
        float acc[8] = {0.f, 0.f, 0.f, 0.f, 0.f, 0.f, 0.f, 0.f};
        gather_h8(P.csr_in, P.ya, half ? mid : e0, half ? e1 : mid, acc);
#pragma unroll
        for (int k = 0; k < 8; k++) acc[k] += __shfl_xor(acc[k], 1);
        if (!half) {
            float bv = P.bn[v];
            const float4* qp = (const float4*)(P.q + (size_t)v * DD);
            float4 q0 = qp[0], q1 = qp[1];
            float hq[8] = {q0.x, q0.y, q0.z, q0.w, q1.x, q1.y, q1.z, q1.w};
            __half2* hp = P.hm + (size_t)v * DD;
#pragma unroll
            for (int k = 0; k < DD; k++) {
                float hval = fmaf(bv, acc[k], P.b2w[k] + hq[k]);
                __half2 cur = hp[k];
                cur.x = __float2half(hval);
                hp[k] = cur;
            }
        }
    }
    gsync(P.bar, sense);

    // ---- phase J: gravity gradient, 4 thr/node (dir x half-range) ----
    for (int t = gtid; t < 4 * P.N; t += gstr) {
        int v = t >> 2, sub = t & 3, dir = sub >> 1, half = sub & 1;
        const uint4* srec = (const uint4*)(P.hm + (size_t)v * DD);
        uint4 s0 = srec[0], s1 = srec[1];
        float hv[8], mv[8];
        unpack_hm(s0, s1, hv, mv);
        const int* start = dir ? P.start_out : P.start_in;
        const int* csr   = dir ? P.csr_out   : P.csr_in;
        int e0 = start[v], e1 = start[v + 1];
        int mid = e0 + ((e1 - e0) >> 1);
        int e = half ? mid : e0, hiE = half ? e1 : mid;
        float coef = -0.5f * P.grav[0];
        float acc[8] = {0.f, 0.f, 0.f, 0.f, 0.f, 0.f, 0.f, 0.f};
        for (; e + 1 < hiE; e += 2) {
            int u0 = csr[e], u1 = csr[e + 1];
            const uint4* r0p = (const uint4*)(P.hm + (size_t)u0 * DD);
            const uint4* r1p = (const uint4*)(P.hm + (size_t)u1 * DD);
            uint4 x0 = r0p[0], x1 = r0p[1], y0 = r1p[0], y1 = r1p[1];
            float hu0[8], mu0[8], hu1[8], mu1[8];
            unpack_hm(x0, x1, hu0, mu0);
            unpack_hm(y0, y1, hu1, mu1);
            float d0[8], d1[8];
            float e20 = 0.f, S0 = 0.f, e21 = 0.f, S1 = 0.f;
#pragma unroll
            for (int k = 0; k < 8; k++) {
                d0[k] = hv[k] - hu0[k];
                d1[k] = hv[k] - hu1[k];
                e20 = fmaf(d0[k], d0[k], e20);
                e21 = fmaf(d1[k], d1[k], e21);
                S0 = fmaf(mv[k], mu0[k], S0);
                S1 = fmaf(mv[k], mu1[k], S1);
            }
            float r0 = rsqrtf(e20), r1 = rsqrtf(e21);
            float c0 = coef * S0 * r0 * r0 * r0;
            float c1 = coef * S1 * r1 * r1 * r1;
#pragma unroll
            for (int k = 0; k < 8; k++)
                acc[k] = fmaf(c0, d0[k], fmaf(c1, d1[k], acc[k]));
        }
        if (e < hiE) {
            int u = csr[e];
            const uint4* rp = (const uint4*)(P.hm + (size_t)u * DD);
            uint4 x0 = rp[0], x1 = rp[1];
            float hu[8], mu[8];
            unpack_hm(x0, x1, hu, mu);
            float df[8];
            float e2 = 0.f, S = 0.f;
#pragma unroll
            for (int k = 0; k < 8; k++) {
                df[k] = hv[k] - hu[k];
                e2 = fmaf(df[k], df[k], e2);
                S = fmaf(mv[k], mu[k], S);
            }
            float r = rsqrtf(e2);
            float c = coef * S * r * r * r;
#pragma unroll
            for (int k = 0; k < 8; k++) acc[k] = fmaf(c, df[k], acc[k]);
        }
#pragma unroll
        for (int k = 0; k < 8; k++) acc[k] += __shfl_xor(acc[k], 1);
#pragma unroll
        for (int k = 0; k < 8; k++) acc[k] += __shfl_xor(acc[k], 2);
        if (sub == 0) {
            float4* gp = (float4*)(P.gh + (size_t)v * DD);
            gp[0] = make_float4(acc[0], acc[1], acc[2], acc[3]);
            gp[1] = make_float4(acc[4], acc[5], acc[6], acc[7]);
            float bv = P.bn[v];
            __half2* bp = (__half2*)(P.bgh + (size_t)v * DD);
            bp[0] = __floats2half2_rn(bv * acc[0], bv * acc[1]);
            bp[1] = __floats2half2_rn(bv * acc[2], bv * acc[3]);
            bp[2] = __floats2half2_rn(bv * acc[4], bv * acc[5]);
            bp[3] = __floats2half2_rn(bv * acc[6], bv * acc[7]);
        }
    }
    gsync(P.bar, sense);

    // ---- phase K: gq2 = AggOut(bgh), 2 thr/node ----
    for (int t = gtid; t < 2 * P.N; t += gstr) {
        int v = t >> 1, half = t & 1;
        int e0 = P.start_out[v], e1 = P.start_out[v + 1];
        int mid = e0 + ((e1 - e0) >> 1);
        float acc[8] = {0.f, 0.f, 0.f, 0.f, 0.f, 0.f, 0.f, 0.f};
        gather_h8(P.csr_out, P.bgh, half ? mid : e0, half ? e1 : mid, acc);
#pragma unroll
        for (int k = 0; k < 8; k++) acc[k] += __shfl_xor(acc[k], 1);
        if (!half) {
            float4* yp = (float4*)(P.gq2 + (size_t)v * DD);
            yp[0] = make_float4(acc[0], acc[1], acc[2], acc[3]);
            yp[1] = make_float4(acc[4], acc[5], acc[6], acc[7]);
        }
    }
    gsync(P.bar, sense);

    // ---- phase L: MLP backward (weights still live in LDS from phase H) ----
    for (int t = gtid; t < 16 * P.N; t += gstr) {
        int v = t >> 4, l16 = t & 15, sub = (t >> 3) & 1, d = t & 7;
        float bv = P.bn[v], av = P.a[v];
        float zl = bv * P.agg1[(size_t)v * DD + d];
        float gl = P.gq2[(size_t)v * DD + d];
        float z[DD], gq[DD];
#pragma unroll
        for (int k = 0; k < DD; k++) { z[k] = __shfl(zl, k, 16); gq[k] = __shfl(gl, k, 16); }
        float gz[DD] = {0.f, 0.f, 0.f, 0.f, 0.f, 0.f, 0.f, 0.f};
        for (int c = 0; c < HH / 16; c += 2) {
            int j0 = (c << 4) | l16, j1 = j0 + 16;
            const float4* w0 = (const float4*)(sW + j0 * WPITCH);
            const float4* w1 = (const float4*)(sW + j1 * WPITCH);
            float4 wa0 = w0[0], wb0 = w0[1], va0 = w0[2], vb0 = w0[3];
            float4 wa1 = w1[0], wb1 = w1[1], va1 = w1[2], vb1 = w1[3];
            float ua0 = fmaf(z[1], wa0.y, fmaf(z[0], wa0.x, sb1[j0]));
            ua0 = fmaf(z[3], wa0.w, fmaf(z[2], wa0.z, ua0));
            float ub0 = fmaf(z[5], wb0.y, z[4] * wb0.x);
            ub0 = fmaf(z[7], wb0.w, fmaf(z[6], wb0.z, ub0));
            float ua1 = fmaf(z[1], wa1.y, fmaf(z[0], wa1.x, sb1[j1]));
            ua1 = fmaf(z[3], wa1.w, fmaf(z[2], wa1.z, ua1));
            float ub1 = fmaf(z[5], wb1.y, z[4] * wb1.x);
            ub1 = fmaf(z[7], wb1.w, fmaf(z[6], wb1.z, ub1));
            float u0 = ua0 + ub0, u1 = ua1 + ub1;
            float ga0 = fmaf(gq[1], va0.y, gq[0] * va0.x);
            ga0 = fmaf(gq[3], va0.w, fmaf(gq[2], va0.z, ga0));
            float gb0 = fmaf(gq[5], vb0.y, gq[4] * vb0.x);
            gb0 = fmaf(gq[7], vb0.w, fmaf(gq[6], vb0.z, gb0));
            float ga1 = fmaf(gq[1], va1.y, gq[0] * va1.x);
            ga1 = fmaf(gq[3], va1.w, fmaf(gq[2], va1.z, ga1));
            float gb1 = fmaf(gq[5], vb1.y, gq[4] * vb1.x);
            gb1 = fmaf(gq[7], vb1.w, fmaf(gq[6], vb1.z, gb1));
            float g0 = (u0 > 0.f) ? av * (ga0 + gb0) : 0.f;
            float g1 = (u1 > 0.f) ? av * (ga1 + gb1) : 0.f;
            gz[0] = fmaf(g0, wa0.x, gz[0]); gz[1] = fmaf(g0, wa0.y, gz[1]);
            gz[2] = fmaf(g0, wa0.z, gz[2]); gz[3] = fmaf(g0, wa0.w, gz[3]);
            gz[4] = fmaf(g0, wb0.x, gz[4]); gz[5] = fmaf(g0, wb0.y, gz[5]);
            gz[6] = fmaf(g0, wb0.z, gz[6]); gz[7] = fmaf(g0, wb0.w, gz[7]);
            gz[0] = fmaf(g1, wa1.x, gz[0]); gz[1] = fmaf(g1, wa1.y, gz[1]);
            gz[2] = fmaf(g1, wa1.z, gz[2]); gz[3] = fmaf(g1, wa1.w, gz[3]);
            gz[4] = fmaf(g1, wb1.x, gz[4]); gz[5] = fmaf(g1, wb1.y, gz[5]);
            gz[6] = fmaf(g1, wb1.z, gz[6]); gz[7] = fmaf(g1, wb1.w, gz[7]);
        }
#pragma unroll
        for (int m = 1; m < 16; m <<= 1)
#pragma unroll
            for (int k = 0; k < DD; k++) gz[k] += __shfl_xor(gz[k], m);
        float out_l = gz[0];
#pragma unroll
        for (int k = 1; k < DD; k++) out_l = (d == k) ? gz[k] : out_l;
        if (!sub) P.gz1b[(size_t)v * DD + d] = __float2half(bv * out_l);
    }
    gsync(P.bar, sense);

    // ---- phase M: out[:, :D] = gh + a * AggOut(gz1b), 2 thr/node ----
    for (int t = gtid; t < 2 * P.N; t += gstr) {
        int v = t >> 1, half = t & 1;
        int e0 = P.start_out[v], e1 = P.start_out[v + 1];
        int mid = e0 + ((e1 - e0) >> 1);
        float acc[8] = {0.f, 0.f, 0.f, 0.f, 0.f, 0.f, 0.f, 0.f};
        gather_h8(P.csr_out, P.gz1b, half ? mid : e0, half ? e1 : mid, acc);
#pragma unroll
        for (int k = 0; k < 8; k++) acc[k] += __shfl_xor(acc[k], 1);
        if (!half) {
            float av = P.a[v];
            const float4* gp = (const float4*)(P.gh + (size_t)v * DD);
            float4 g0 = gp[0], g1 = gp[1];
            float4* op = (float4*)(P.out + (size_t)v * 2 * DD);
            op[0] = make_float4(fmaf(av, acc[0], g0.x), fmaf(av, acc[1], g0.y),
                                fmaf(av, acc[2], g0.z), fmaf(av, acc[3], g0.w));
            op[1] = make_float4(fmaf(av, acc[4], g1.x), fmaf(av, acc[5], g1.y),
                                fmaf(av, acc[6], g1.z), fmaf(av, acc[7], g1.w));
        }
    }
}

// ============================== launch =====================================

extern "C" void kernel_launch(void* const* d_in, const int* in_sizes, int n_in,
                              void* d_out, int out_size, void* d_ws, size_t ws_size,
                              hipStream_t stream) {
    const float* q    = (const float*)d_in[0];
    const float* p    = (const float*)d_in[1];
    const float* M    = (const float*)d_in[2];
    const int*   src  = (const int*)d_in[3];
    const int*   dst  = (const int*)d_in[4];
    const float* W1   = (const float*)d_in[5];
    const float* b1   = (const float*)d_in[6];
    const float* W2   = (const float*)d_in[7];
    const float* b2   = (const float*)d_in[8];
    const float* grav = (const float*)d_in[9];
    float* out = (float*)d_out;

    int N = in_sizes[0] / DD;
    int E = in_sizes[3];
    size_t n = (size_t)N;
    int NB = (N + 511) >> 9;
    int NC = (E + CH - 1) / CH;

    // ---- data region (46N 4-byte words) ----
    float*   ws   = (float*)d_ws;
    float*   a_   = ws;             // N
    float*   b_   = ws + n;         // N
    float*   qn   = ws + 2  * n;    // 8N f32 (reused as gq2 after phase G)
    float*   agg1 = ws + 10 * n;    // 8N f32 (live through bwd)
    float*   gh   = ws + 18 * n;    // 8N f32
    __half2* hm   = (__half2*)(ws + 26 * n);  // 8N half2 (8N words)
    __half*  ya   = (__half*)(ws + 34 * n);   // 8N half (4N words)
    __half*  bgh  = (__half*)(ws + 38 * n);   // 8N half (4N words)
    __half*  gz1b = (__half*)(ws + 42 * n);   // 8N half (4N words)
    float*   gq2  = qn;

    // ---- int region ----
    int* iw        = (int*)(ws + 46 * n);
    int* csr_in    = iw;                       // E
    int* csr_out   = iw + (size_t)E;           // E
    int* start_in  = iw + 2 * (size_t)E;       // N+1
    int* start_out = start_in + n + 1;         // N+1
    int* gHistIn   = start_out + n + 1;        // 256
    int* gHistOut  = gHistIn + 256;            // 256
    int* cStartIn  = gHistOut + 256;           // NB+1
    int* cStartOut = cStartIn + NB + 1;        // NB+1
    int* cCurIn    = cStartOut + NB + 1;       // NB
    int* cCurOut   = cCurIn + NB;              // NB
    int* iwEnd     = cCurOut + NB;
    float* W12p    = (float*)iwEnd;            // HH*WPITCH = 5120 floats
    int* intAfter  = (int*)(W12p + HH * WPITCH);
    // partition scratch: both dirs alias the data region (dead during build)
    int* P_in  = (E <= 16 * (long long)n) ? (int*)ws            : intAfter;
    int* P_out = (E <= 16 * (long long)n) ? (int*)(ws + 16 * n) : intAfter + E;
    int* barp  = (E <= 16 * (long long)n) ? intAfter            : intAfter + 2 * (size_t)E;

    Params prm;
    prm.q = q; prm.p = p; prm.M = M;
    prm.W1 = W1; prm.b1w = b1; prm.W2 = W2; prm.b2w = b2; prm.grav = grav;
    prm.src = src; prm.dst = dst;
    prm.out = out;
    prm.a = a_; prm.bn = b_; prm.qn = qn; prm.agg1 = agg1; prm.gh = gh;
    prm.W12p = W12p;
    prm.hm = hm; prm.ya = ya; prm.bgh = bgh; prm.gz1b = gz1b; prm.gq2 = gq2;
    prm.csr_in = csr_in; prm.csr_out = csr_out;
    prm.start_in = start_in; prm.start_out = start_out;
    prm.gHistIn = gHistIn; prm.gHistOut = gHistOut;
    prm.cStartIn = cStartIn; prm.cStartOut = cStartOut;
    prm.cCurIn = cCurIn; prm.cCurOut = cCurOut;
    prm.P_in = P_in; prm.P_out = P_out;
    prm.bar = barp;
    prm.N = N; prm.E = E; prm.NB = NB; prm.NC = NC;

    // zero the global hists (512 ints) and the barrier state (2 ints)
    hipMemsetAsync(gHistIn, 0, 512 * sizeof(int), stream);
    hipMemsetAsync(barp, 0, 2 * sizeof(int), stream);

    mega<<<dim3(NBLK), dim3(256), 0, stream>>>(prm);
}

// Round 3
// 1103.028 us; speedup vs baseline: 1.8172x; 1.8172x over previous
//
#include <hip/hip_runtime.h>
#include <hip/hip_fp16.h>

#define DD 8
#define HH 256
#define CH 4096          // edges per chunk
#define PAYBITS 17       // N <= 131072
#define PAYMASK 0x1FFFF
#define WPITCH 20        // LDS weight row pitch (floats): conflict-free
#define NBLK 768         // 3 blocks/CU x 256 CUs -- guaranteed by launch_bounds(256,3)

// Barrier state slot layout (ints, 64B-separated where hammered)
#define SL_REG   0       // registration counter
#define SL_XCNT  16      // [16..23] per-XCD block counts (registration)
#define SL_XARR  32      // +16*x   per-XCD monotonic arrive counters
#define SL_XRDY  192     // +16*x   per-XCD ready epochs
#define SL_GAR   352     // global master arrive counter (monotonic)
#define SL_TOTAL 512

// Fused persistent kernel. Round-2 lesson (PMC-verified): per-BLOCK agent
// fences = 768 redundant buffer_wbl2 L2 tag-walks + 8448 full-L2 invalidates
// per launch -> 1.9GB refetch, 2004us. Fix: two-level barrier. The LAST
// same-XCD arriver is "XCD master": it alone does the agent release fence
// (one wbl2 flushes the whole XCD L2 = all same-XCD blocks' stores, since
// L1 is write-through and __syncthreads drains vmcnt pre-arrive) and, after
// the global epoch, one agent acquire fence (one L2 inv) BEFORE releasing
// its XCD's blocks. Non-masters only invalidate their per-CU L1 (flagless
// buffer_inv). All counters monotonic-epoch: no reset races.

struct Params {
    const float *q, *p, *M, *W1, *b1w, *W2, *b2w, *grav;
    const int *src, *dst;
    float *out;
    float *a, *bn, *qn, *agg1, *gh, *W12p;
    __half2 *hm;
    __half *ya, *bgh, *gz1b;
    float *gq2;                 // alias of qn
    int *csr_in, *csr_out, *start_in, *start_out;
    int *gHistIn, *gHistOut, *cStartIn, *cStartOut, *cCurIn, *cCurOut;
    int *P_in, *P_out;
    int *bar;                   // SL_TOTAL ints, memset to 0
    int N, E, NB, NC;
};

// ------------------- record unpack/accumulate helpers -----------------------
static __device__ __forceinline__
void acc_h8(uint4 r, float acc[8]) {
    float2 f;
    f = __half22float2(*(__half2*)&r.x); acc[0] += f.x; acc[1] += f.y;
    f = __half22float2(*(__half2*)&r.y); acc[2] += f.x; acc[3] += f.y;
    f = __half22float2(*(__half2*)&r.z); acc[4] += f.x; acc[5] += f.y;
    f = __half22float2(*(__half2*)&r.w); acc[6] += f.x; acc[7] += f.y;
}

static __device__ __forceinline__
void unpack_hm(uint4 r0, uint4 r1, float h[8], float m[8]) {
    float2 f;
    f = __half22float2(*(__half2*)&r0.x); h[0] = f.x; m[0] = f.y;
    f = __half22float2(*(__half2*)&r0.y); h[1] = f.x; m[1] = f.y;
    f = __half22float2(*(__half2*)&r0.z); h[2] = f.x; m[2] = f.y;
    f = __half22float2(*(__half2*)&r0.w); h[3] = f.x; m[3] = f.y;
    f = __half22float2(*(__half2*)&r1.x); h[4] = f.x; m[4] = f.y;
    f = __half22float2(*(__half2*)&r1.y); h[5] = f.x; m[5] = f.y;
    f = __half22float2(*(__half2*)&r1.z); h[6] = f.x; m[6] = f.y;
    f = __half22float2(*(__half2*)&r1.w); h[7] = f.x; m[7] = f.y;
}

static __device__ __forceinline__
void gather_h8(const int* __restrict__ csr, const __half* __restrict__ x,
               int e, int e1, float acc[8]) {
    for (; e + 3 < e1; e += 4) {
        int u0 = csr[e], u1 = csr[e + 1], u2 = csr[e + 2], u3 = csr[e + 3];
        uint4 r0 = *(const uint4*)(x + (size_t)u0 * DD);
        uint4 r1 = *(const uint4*)(x + (size_t)u1 * DD);
        uint4 r2 = *(const uint4*)(x + (size_t)u2 * DD);
        uint4 r3 = *(const uint4*)(x + (size_t)u3 * DD);
        acc_h8(r0, acc); acc_h8(r1, acc); acc_h8(r2, acc); acc_h8(r3, acc);
    }
    for (; e < e1; e++) {
        uint4 r = *(const uint4*)(x + (size_t)csr[e] * DD);
        acc_h8(r, acc);
    }
}

// ============================ the mega kernel ===============================

__launch_bounds__(256, 3)
__global__ void mega(Params P) {
    __shared__ __align__(16) float smf[HH * WPITCH + HH];   // 21.5 KB, aliased
    int* smi = (int*)smf;
    const int tid  = threadIdx.x;
    const int gtid = blockIdx.x * 256 + tid;
    const int gstr = gridDim.x * 256;
    int* Bar = P.bar;

    // ---- registration: discover per-XCD block count + populated-XCD count ---
    int xcd = 0, xcnt_ = 1, nx_ = 1, ep = 0;
    if (tid == 0) {
        int xr;
        asm volatile("s_getreg_b32 %0, hwreg(HW_REG_XCC_ID)" : "=s"(xr));
        xcd = xr & 7;
        int pv = __hip_atomic_fetch_add(&Bar[SL_XCNT + xcd], 1,
                                        __ATOMIC_RELAXED, __HIP_MEMORY_SCOPE_AGENT);
        asm volatile("" :: "v"(pv));   // force RMW completion before reg-add
        __hip_atomic_fetch_add(&Bar[SL_REG], 1,
                               __ATOMIC_RELAXED, __HIP_MEMORY_SCOPE_AGENT);
        while (__hip_atomic_load(&Bar[SL_REG], __ATOMIC_RELAXED,
                                 __HIP_MEMORY_SCOPE_AGENT) < NBLK)
            __builtin_amdgcn_s_sleep(2);
        nx_ = 0;
#pragma unroll
        for (int x = 0; x < 8; x++) {
            int c = __hip_atomic_fetch_add(&Bar[SL_XCNT + x], 0,
                                           __ATOMIC_RELAXED, __HIP_MEMORY_SCOPE_AGENT);
            if (x == xcd) xcnt_ = c;
            if (c > 0) nx_++;
        }
    }
    __syncthreads();

    // ---- two-level grid barrier (one L2 wb + one L2 inv per XCD) ----
    auto gsync = [&]() {
        __syncthreads();                 // drains vmcnt: block stores are in L2
        if (tid == 0) {
            ++ep;
            int prev = __hip_atomic_fetch_add(&Bar[SL_XARR + xcd * 16], 1,
                                              __ATOMIC_RELAXED, __HIP_MEMORY_SCOPE_AGENT);
            if (prev == ep * xcnt_ - 1) {
                // XCD master: flush this XCD's L2 (all same-XCD stores)
                __builtin_amdgcn_fence(__ATOMIC_RELEASE, "agent");
                __hip_atomic_fetch_add(&Bar[SL_GAR], 1,
                                       __ATOMIC_RELAXED, __HIP_MEMORY_SCOPE_AGENT);
                while (__hip_atomic_load(&Bar[SL_GAR], __ATOMIC_RELAXED,
                                         __HIP_MEMORY_SCOPE_AGENT) < nx_ * ep)
                    __builtin_amdgcn_s_sleep(1);
                // one L2 (+own L1) invalidate per XCD, before releasing it
                __builtin_amdgcn_fence(__ATOMIC_ACQUIRE, "agent");
                __hip_atomic_store(&Bar[SL_XRDY + xcd * 16], ep,
                                   __ATOMIC_RELAXED, __HIP_MEMORY_SCOPE_AGENT);
            } else {
                while (__hip_atomic_load(&Bar[SL_XRDY + xcd * 16], __ATOMIC_RELAXED,
                                         __HIP_MEMORY_SCOPE_AGENT) < ep)
                    __builtin_amdgcn_s_sleep(1);
                // L2 already fresh (master inv'd); kill only this CU's L1
                asm volatile("buffer_inv" ::: "memory");
            }
        }
        __syncthreads();
    };

    // ---- prologue (no cross-block deps): weight pack + start[N]=E ----
    if (gtid == 0) { P.start_in[P.N] = P.E; P.start_out[P.N] = P.E; }
    for (int t = gtid; t < HH * DD; t += gstr) {
        int j = t >> 3, dd = t & 7;
        P.W12p[j * WPITCH + dd]     = P.W1[dd * HH + j];
        P.W12p[j * WPITCH + 8 + dd] = P.W2[j * DD + dd];
    }

    // ---- phase B: coarse per-chunk histograms (gHist zeroed by memset) ----
    for (int ch = blockIdx.x; ch < P.NC; ch += gridDim.x) {
        int* hIn = smi; int* hOut = smi + 256;
        hIn[tid] = 0; hOut[tid] = 0;
        __syncthreads();
        int lo = ch * CH, hi = min(lo + CH, P.E);
        for (int i = lo + tid; i < hi; i += 256) {
            atomicAdd(&hIn[P.dst[i] >> 9], 1);
            atomicAdd(&hOut[P.src[i] >> 9], 1);
        }
        __syncthreads();
        if (tid < P.NB) {
            int ci = hIn[tid], co = hOut[tid];
            if (ci) atomicAdd(&P.gHistIn[tid], ci);
            if (co) atomicAdd(&P.gHistOut[tid], co);
        }
        __syncthreads();
    }
    gsync();

    // ---- phase C: chunk-level exclusive scan (block 0 only) ----
    if (blockIdx.x == 0) {
#pragma unroll
        for (int dir = 0; dir < 2; dir++) {
            const int* gh_ = dir ? P.gHistOut : P.gHistIn;
            int* cs = dir ? P.cStartOut : P.cStartIn;
            int* cc = dir ? P.cCurOut : P.cCurIn;
            int v = (tid < P.NB) ? gh_[tid] : 0;
            smi[tid] = v;
            __syncthreads();
            for (int off = 1; off < 256; off <<= 1) {
                int t = (tid >= off) ? smi[tid - off] : 0;
                __syncthreads();
                smi[tid] += t;
                __syncthreads();
            }
            if (tid < P.NB) { int ex = smi[tid] - v; cs[tid] = ex; cc[tid] = ex; }
            if (tid == 0) cs[P.NB] = P.E;
            __syncthreads();
        }
    }
    gsync();

    // ---- phase D: partition into per-(chunk, 512-node-bin) runs ----
    for (int vb = blockIdx.x; vb < 2 * P.NC; vb += gridDim.x) {
        int dir = vb >= P.NC;
        int ch  = dir ? vb - P.NC : vb;
        const int* key = dir ? P.src : P.dst;
        const int* pay = dir ? P.dst : P.src;
        int* cCur = dir ? P.cCurOut : P.cCurIn;
        int* Pp   = dir ? P.P_out   : P.P_in;
        int* h = smi;
        h[tid] = 0;
        __syncthreads();
        int lo = ch * CH, hi = min(lo + CH, P.E);
        for (int i = lo + tid; i < hi; i += 256)
            atomicAdd(&h[key[i] >> 9], 1);
        __syncthreads();
        if (tid < P.NB) {
            int c = h[tid];
            h[tid] = c ? atomicAdd(&cCur[tid], c) : 0;
        }
        __syncthreads();
        for (int i = lo + tid; i < hi; i += 256) {
            int k = key[i];
            int pos = atomicAdd(&h[k >> 9], 1);
            Pp[pos] = ((k & 511) << PAYBITS) | pay[i];
        }
        __syncthreads();
    }
    gsync();

    // ---- phase E: fine sort within 512-node bins -> CSR ----
    for (int vb = blockIdx.x; vb < 2 * P.NB; vb += gridDim.x) {
        int dir = vb >= P.NB;
        int b   = dir ? vb - P.NB : vb;
        const int* cStart = dir ? P.cStartOut : P.cStartIn;
        const int* Pp     = dir ? P.P_out     : P.P_in;
        int* start        = dir ? P.start_out : P.start_in;
        int* csr          = dir ? P.csr_out   : P.csr_in;
        int* cnt = smi;              // 512
        int* scn = smi + 512;        // 512
        int* ps  = smi + 1024;       // 256
        int lo = cStart[b], hi = cStart[b + 1];
        cnt[tid] = 0; cnt[tid + 256] = 0;
        __syncthreads();
        for (int i = lo + tid; i < hi; i += 256)
            atomicAdd(&cnt[Pp[i] >> PAYBITS], 1);
        __syncthreads();
        int c0 = cnt[2 * tid], c1 = cnt[2 * tid + 1];
        int pair = c0 + c1;
        ps[tid] = pair;
        __syncthreads();
        for (int off = 1; off < 256; off <<= 1) {
            int t = (tid >= off) ? ps[tid - off] : 0;
            __syncthreads();
            ps[tid] += t;
            __syncthreads();
        }
        int excl = ps[tid] - pair;
        scn[2 * tid] = excl;
        scn[2 * tid + 1] = excl + c0;
        __syncthreads();
#pragma unroll
        for (int k = 0; k < 2; k++) {
            int i = tid + k * 256;
            int base = lo + scn[i];
            int node = (b << 9) + i;
            if (node < P.N) start[node] = base;
            cnt[i] = base;           // reuse as cursor
        }
        __syncthreads();
        for (int i = lo + tid; i < hi; i += 256) {
            int pv = Pp[i];
            int pos = atomicAdd(&cnt[pv >> PAYBITS], 1);
            csr[pos] = pv & PAYMASK;
        }
        __syncthreads();
    }
    gsync();

    // ---- phase F: per-node prep (norms, masses, dHdP) ----
    for (int v = gtid; v < P.N; v += gstr) {
        int ei1 = (v + 1 < P.N) ? P.start_in[v + 1]  : P.E;
        int eo1 = (v + 1 < P.N) ? P.start_out[v + 1] : P.E;
        float din  = (float)(ei1 - P.start_in[v]);
        float dout = (float)(eo1 - P.start_out[v]);
        float av = 1.0f / sqrtf(dout > 0.f ? dout : 1.f);
        float bv = 1.0f / sqrtf(din  > 0.f ? din  : 1.f);
        P.a[v] = av; P.bn[v] = bv;
#pragma unroll
        for (int d = 0; d < DD; d++) {
            float m = P.M[(size_t)v * DD * DD + d * (DD + 1)];
            __half2 hmv;
            hmv.x = __float2half(0.f);
            hmv.y = __float2half(m);
            P.hm[(size_t)v * DD + d] = hmv;
            P.qn[(size_t)v * DD + d] = av * P.q[(size_t)v * DD + d];
            P.out[(size_t)v * 2 * DD + DD + d] = P.p[(size_t)v * DD + d] / m;
        }
    }
    gsync();

    // ---- phase G: agg1 = AggIn(a*q), 2 thr/node ----
    for (int t = gtid; t < 2 * P.N; t += gstr) {
        int v = t >> 1, half = t & 1;
        int e0 = P.start_in[v], e1 = P.start_in[v + 1];
        int mid = e0 + ((e1 - e0) >> 1);
        int e = half ? mid : e0, hiE = half ? e1 : mid;
        float acc[8] = {0.f, 0.f, 0.f, 0.f, 0.f, 0.f, 0.f, 0.f};
        for (; e + 1 < hiE; e += 2) {
            int u0 = P.csr_in[e], u1 = P.csr_in[e + 1];
            const float4* p0 = (const float4*)(P.qn + (size_t)u0 * DD);
            const float4* p1 = (const float4*)(P.qn + (size_t)u1 * DD);
            float4 a0 = p0[0], b0 = p0[1], a1 = p1[0], b1 = p1[1];
            acc[0] += a0.x + a1.x; acc[1] += a0.y + a1.y;
            acc[2] += a0.z + a1.z; acc[3] += a0.w + a1.w;
            acc[4] += b0.x + b1.x; acc[5] += b0.y + b1.y;
            acc[6] += b0.z + b1.z; acc[7] += b0.w + b1.w;
        }
        if (e < hiE) {
            const float4* pp = (const float4*)(P.qn + (size_t)P.csr_in[e] * DD);
            float4 a0 = pp[0], b0 = pp[1];
            acc[0] += a0.x; acc[1] += a0.y; acc[2] += a0.z; acc[3] += a0.w;
            acc[4] += b0.x; acc[5] += b0.y; acc[6] += b0.z; acc[7] += b0.w;
        }
#pragma unroll
        for (int k = 0; k < 8; k++) acc[k] += __shfl_xor(acc[k], 1);
        if (!half) {
            float4* yp = (float4*)(P.agg1 + (size_t)v * DD);
            yp[0] = make_float4(acc[0], acc[1], acc[2], acc[3]);
            yp[1] = make_float4(acc[4], acc[5], acc[6], acc[7]);
        }
    }
    gsync();

    // ---- phase H: MLP forward, 16 lanes/node; weights -> LDS once/block ----
    float* sW  = smf;
    float* sb1 = smf + HH * WPITCH;
    for (int i = tid; i < HH * WPITCH; i += 256) sW[i] = P.W12p[i];
    for (int i = tid; i < HH; i += 256) sb1[i] = P.b1w[i];
    __syncthreads();
    for (int t = gtid; t < 16 * P.N; t += gstr) {
        int v = t >> 4, l16 = t & 15, sub = (t >> 3) & 1, d = t & 7;
        float zl = P.bn[v] * P.agg1[(size_t)v * DD + d];
        float z[DD];
#pragma unroll
        for (int k = 0; k < DD; k++) z[k] = __shfl(zl, k, 16);
        float acc[DD] = {0.f, 0.f, 0.f, 0.f, 0.f, 0.f, 0.f, 0.f};
        for (int c = 0; c < HH / 16; c += 2) {
            int j0 = (c << 4) | l16, j1 = j0 + 16;
            const float4* w0 = (const float4*)(sW + j0 * WPITCH);
            const float4* w1 = (const float4*)(sW + j1 * WPITCH);
            float4 wa0 = w0[0], wb0 = w0[1], va0 = w0[2], vb0 = w0[3];
            float4 wa1 = w1[0], wb1 = w1[1], va1 = w1[2], vb1 = w1[3];
            float ua0 = fmaf(z[1], wa0.y, fmaf(z[0], wa0.x, sb1[j0]));
            ua0 = fmaf(z[3], wa0.w, fmaf(z[2], wa0.z, ua0));
            float ub0 = fmaf(z[5], wb0.y, z[4] * wb0.x);
            ub0 = fmaf(z[7], wb0.w, fmaf(z[6], wb0.z, ub0));
            float ua1 = fmaf(z[1], wa1.y, fmaf(z[0], wa1.x, sb1[j1]));
            ua1 = fmaf(z[3], wa1.w, fmaf(z[2], wa1.z, ua1));
            float ub1 = fmaf(z[5], wb1.y, z[4] * wb1.x);
            ub1 = fmaf(z[7], wb1.w, fmaf(z[6], wb1.z, ub1));
            float h0 = fmaxf(ua0 + ub0, 0.f);
            float h1 = fmaxf(ua1 + ub1, 0.f);
            acc[0] = fmaf(h0, va0.x, acc[0]); acc[1] = fmaf(h0, va0.y, acc[1]);
            acc[2] = fmaf(h0, va0.z, acc[2]); acc[3] = fmaf(h0, va0.w, acc[3]);
            acc[4] = fmaf(h0, vb0.x, acc[4]); acc[5] = fmaf(h0, vb0.y, acc[5]);
            acc[6] = fmaf(h0, vb0.z, acc[6]); acc[7] = fmaf(h0, vb0.w, acc[7]);
            acc[0] = fmaf(h1, va1.x, acc[0]); acc[1] = fmaf(h1, va1.y, acc[1]);
            acc[2] = fmaf(h1, va1.z, acc[2]); acc[3] = fmaf(h1, va1.w, acc[3]);
            acc[4] = fmaf(h1, vb1.x, acc[4]); acc[5] = fmaf(h1, vb1.y, acc[5]);
            acc[6] = fmaf(h1, vb1.z, acc[6]); acc[7] = fmaf(h1, vb1.w, acc[7]);
        }
#pragma unroll
        for (int m = 1; m < 16; m <<= 1)
#pragma unroll
            for (int k = 0; k < DD; k++) acc[k] += __shfl_xor(acc[k], m);
        float yl = acc[0];
#pragma unroll
        for (int k = 1; k < DD; k++) yl = (d == k) ? acc[k] : yl;
        if (!sub) P.ya[(size_t)v * DD + d] = __float2half(P.a[v] * yl);
    }
    gsync();

    // ---- phase I: h = b*AggIn(ya) + b2 + q -> .x halves of hm ----
    for (int t = gtid; t < 2 * P.N; t += gstr) {
        int v = t >> 1, half = t & 1;
        int e0 = P.start_in[v], e1 = P.start_in[v + 1];
        int mid = e0 + ((e1 - e0) >> 1);
        float acc[8] = {0.f, 0.f, 0.f, 0.f, 0.f, 0.f, 0.f, 0.f};
        gather_h8(P.csr_in, P.ya, half ? mid : e0, half ? e1 : mid, acc);
#pragma unroll
        for (int k = 0; k < 8; k++) acc[k] += __shfl_xor(acc[k], 1);
        if (!half) {
            float bv = P.bn[v];
            const float4* qp = (const float4*)(P.q + (size_t)v * DD);
            float4 q0 = qp[0], q1 = qp[1];
            float hq[8] = {q0.x, q0.y, q0.z, q0.w, q1.x, q1.y, q1.z, q1.w};
            __half2* hp = P.hm + (size_t)v * DD;
#pragma unroll
            for (int k = 0; k < DD; k++) {
                float hval = fmaf(bv, acc[k], P.b2w[k] + hq[k]);
                __half2 cur = hp[k];
                cur.x = __float2half(hval);
                hp[k] = cur;
            }
        }
    }
    gsync();

    // ---- phase J: gravity gradient, 4 thr/node (dir x half-range) ----
    for (int t = gtid; t < 4 * P.N; t += gstr) {
        int v = t >> 2, sub = t & 3, dir = sub >> 1, half = sub & 1;
        const uint4* srec = (const uint4*)(P.hm + (size_t)v * DD);
        uint4 s0 = srec[0], s1 = srec[1];
        float hv[8], mv[8];
        unpack_hm(s0, s1, hv, mv);
        const int* start = dir ? P.start_out : P.start_in;
        const int* csr   = dir ? P.csr_out   : P.csr_in;
        int e0 = start[v], e1 = start[v + 1];
        int mid = e0 + ((e1 - e0) >> 1);
        int e = half ? mid : e0, hiE = half ? e1 : mid;
        float coef = -0.5f * P.grav[0];
        float acc[8] = {0.f, 0.f, 0.f, 0.f, 0.f, 0.f, 0.f, 0.f};
        for (; e + 1 < hiE; e += 2) {
            int u0 = csr[e], u1 = csr[e + 1];
            const uint4* r0p = (const uint4*)(P.hm + (size_t)u0 * DD);
            const uint4* r1p = (const uint4*)(P.hm + (size_t)u1 * DD);
            uint4 x0 = r0p[0], x1 = r0p[1], y0 = r1p[0], y1 = r1p[1];
            float hu0[8], mu0[8], hu1[8], mu1[8];
            unpack_hm(x0, x1, hu0, mu0);
            unpack_hm(y0, y1, hu1, mu1);
            float d0[8], d1[8];
            float e20 = 0.f, S0 = 0.f, e21 = 0.f, S1 = 0.f;
#pragma unroll
            for (int k = 0; k < 8; k++) {
                d0[k] = hv[k] - hu0[k];
                d1[k] = hv[k] - hu1[k];
                e20 = fmaf(d0[k], d0[k], e20);
                e21 = fmaf(d1[k], d1[k], e21);
                S0 = fmaf(mv[k], mu0[k], S0);
                S1 = fmaf(mv[k], mu1[k], S1);
            }
            float r0 = rsqrtf(e20), r1 = rsqrtf(e21);
            float c0 = coef * S0 * r0 * r0 * r0;
            float c1 = coef * S1 * r1 * r1 * r1;
#pragma unroll
            for (int k = 0; k < 8; k++)
                acc[k] = fmaf(c0, d0[k], fmaf(c1, d1[k], acc[k]));
        }
        if (e < hiE) {
            int u = csr[e];
            const uint4* rp = (const uint4*)(P.hm + (size_t)u * DD);
            uint4 x0 = rp[0], x1 = rp[1];
            float hu[8], mu[8];
            unpack_hm(x0, x1, hu, mu);
            float df[8];
            float e2 = 0.f, S = 0.f;
#pragma unroll
            for (int k = 0; k < 8; k++) {
                df[k] = hv[k] - hu[k];
                e2 = fmaf(df[k], df[k], e2);
                S = fmaf(mv[k], mu[k], S);
            }
            float r = rsqrtf(e2);
            float c = coef * S * r * r * r;
#pragma unroll
            for (int k = 0; k < 8; k++) acc[k] = fmaf(c, df[k], acc[k]);
        }
#pragma unroll
        for (int k = 0; k < 8; k++) acc[k] += __shfl_xor(acc[k], 1);
#pragma unroll
        for (int k = 0; k < 8; k++) acc[k] += __shfl_xor(acc[k], 2);
        if (sub == 0) {
            float4* gp = (float4*)(P.gh + (size_t)v * DD);
            gp[0] = make_float4(acc[0], acc[1], acc[2], acc[3]);
            gp[1] = make_float4(acc[4], acc[5], acc[6], acc[7]);
            float bv = P.bn[v];
            __half2* bp = (__half2*)(P.bgh + (size_t)v * DD);
            bp[0] = __floats2half2_rn(bv * acc[0], bv * acc[1]);
            bp[1] = __floats2half2_rn(bv * acc[2], bv * acc[3]);
            bp[2] = __floats2half2_rn(bv * acc[4], bv * acc[5]);
            bp[3] = __floats2half2_rn(bv * acc[6], bv * acc[7]);
        }
    }
    gsync();

    // ---- phase K: gq2 = AggOut(bgh), 2 thr/node ----
    for (int t = gtid; t < 2 * P.N; t += gstr) {
        int v = t >> 1, half = t & 1;
        int e0 = P.start_out[v], e1 = P.start_out[v + 1];
        int mid = e0 + ((e1 - e0) >> 1);
        float acc[8] = {0.f, 0.f, 0.f, 0.f, 0.f, 0.f, 0.f, 0.f};
        gather_h8(P.csr_out, P.bgh, half ? mid : e0, half ? e1 : mid, acc);
#pragma unroll
        for (int k = 0; k < 8; k++) acc[k] += __shfl_xor(acc[k], 1);
        if (!half) {
            float4* yp = (float4*)(P.gq2 + (size_t)v * DD);
            yp[0] = make_float4(acc[0], acc[1], acc[2], acc[3]);
            yp[1] = make_float4(acc[4], acc[5], acc[6], acc[7]);
        }
    }
    gsync();

    // ---- phase L: MLP backward (weights still live in LDS from phase H) ----
    for (int t = gtid; t < 16 * P.N; t += gstr) {
        int v = t >> 4, l16 = t & 15, sub = (t >> 3) & 1, d = t & 7;
        float bv = P.bn[v], av = P.a[v];
        float zl = bv * P.agg1[(size_t)v * DD + d];
        float gl = P.gq2[(size_t)v * DD + d];
        float z[DD], gq[DD];
#pragma unroll
        for (int k = 0; k < DD; k++) { z[k] = __shfl(zl, k, 16); gq[k] = __shfl(gl, k, 16); }
        float gz[DD] = {0.f, 0.f, 0.f, 0.f, 0.f, 0.f, 0.f, 0.f};
        for (int c = 0; c < HH / 16; c += 2) {
            int j0 = (c << 4) | l16, j1 = j0 + 16;
            const float4* w0 = (const float4*)(sW + j0 * WPITCH);
            const float4* w1 = (const float4*)(sW + j1 * WPITCH);
            float4 wa0 = w0[0], wb0 = w0[1], va0 = w0[2], vb0 = w0[3];
            float4 wa1 = w1[0], wb1 = w1[1], va1 = w1[2], vb1 = w1[3];
            float ua0 = fmaf(z[1], wa0.y, fmaf(z[0], wa0.x, sb1[j0]));
            ua0 = fmaf(z[3], wa0.w, fmaf(z[2], wa0.z, ua0));
            float ub0 = fmaf(z[5], wb0.y, z[4] * wb0.x);
            ub0 = fmaf(z[7], wb0.w, fmaf(z[6], wb0.z, ub0));
            float ua1 = fmaf(z[1], wa1.y, fmaf(z[0], wa1.x, sb1[j1]));
            ua1 = fmaf(z[3], wa1.w, fmaf(z[2], wa1.z, ua1));
            float ub1 = fmaf(z[5], wb1.y, z[4] * wb1.x);
            ub1 = fmaf(z[7], wb1.w, fmaf(z[6], wb1.z, ub1));
            float u0 = ua0 + ub0, u1 = ua1 + ub1;
            float ga0 = fmaf(gq[1], va0.y, gq[0] * va0.x);
            ga0 = fmaf(gq[3], va0.w, fmaf(gq[2], va0.z, ga0));
            float gb0 = fmaf(gq[5], vb0.y, gq[4] * vb0.x);
            gb0 = fmaf(gq[7], vb0.w, fmaf(gq[6], vb0.z, gb0));
            float ga1 = fmaf(gq[1], va1.y, gq[0] * va1.x);
            ga1 = fmaf(gq[3], va1.w, fmaf(gq[2], va1.z, ga1));
            float gb1 = fmaf(gq[5], vb1.y, gq[4] * vb1.x);
            gb1 = fmaf(gq[7], vb1.w, fmaf(gq[6], vb1.z, gb1));
            float g0 = (u0 > 0.f) ? av * (ga0 + gb0) : 0.f;
            float g1 = (u1 > 0.f) ? av * (ga1 + gb1) : 0.f;
            gz[0] = fmaf(g0, wa0.x, gz[0]); gz[1] = fmaf(g0, wa0.y, gz[1]);
            gz[2] = fmaf(g0, wa0.z, gz[2]); gz[3] = fmaf(g0, wa0.w, gz[3]);
            gz[4] = fmaf(g0, wb0.x, gz[4]); gz[5] = fmaf(g0, wb0.y, gz[5]);
            gz[6] = fmaf(g0, wb0.z, gz[6]); gz[7] = fmaf(g0, wb0.w, gz[7]);
            gz[0] = fmaf(g1, wa1.x, gz[0]); gz[1] = fmaf(g1, wa1.y, gz[1]);
            gz[2] = fmaf(g1, wa1.z, gz[2]); gz[3] = fmaf(g1, wa1.w, gz[3]);
            gz[4] = fmaf(g1, wb1.x, gz[4]); gz[5] = fmaf(g1, wb1.y, gz[5]);
            gz[6] = fmaf(g1, wb1.z, gz[6]); gz[7] = fmaf(g1, wb1.w, gz[7]);
        }
#pragma unroll
        for (int m = 1; m < 16; m <<= 1)
#pragma unroll
            for (int k = 0; k < DD; k++) gz[k] += __shfl_xor(gz[k], m);
        float out_l = gz[0];
#pragma unroll
        for (int k = 1; k < DD; k++) out_l = (d == k) ? gz[k] : out_l;
        if (!sub) P.gz1b[(size_t)v * DD + d] = __float2half(bv * out_l);
    }
    gsync();

    // ---- phase M: out[:, :D] = gh + a * AggOut(gz1b), 2 thr/node ----
    for (int t = gtid; t < 2 * P.N; t += gstr) {
        int v = t >> 1, half = t & 1;
        int e0 = P.start_out[v], e1 = P.start_out[v + 1];
        int mid = e0 + ((e1 - e0) >> 1);
        float acc[8] = {0.f, 0.f, 0.f, 0.f, 0.f, 0.f, 0.f, 0.f};
        gather_h8(P.csr_out, P.gz1b, half ? mid : e0, half ? e1 : mid, acc);
#pragma unroll
        for (int k = 0; k < 8; k++) acc[k] += __shfl_xor(acc[k], 1);
        if (!half) {
            float av = P.a[v];
            const float4* gp = (const float4*)(P.gh + (size_t)v * DD);
            float4 g0 = gp[0], g1 = gp[1];
            float4* op = (float4*)(P.out + (size_t)v * 2 * DD);
            op[0] = make_float4(fmaf(av, acc[0], g0.x), fmaf(av, acc[1], g0.y),
                                fmaf(av, acc[2], g0.z), fmaf(av, acc[3], g0.w));
            op[1] = make_float4(fmaf(av, acc[4], g1.x), fmaf(av, acc[5], g1.y),
                                fmaf(av, acc[6], g1.z), fmaf(av, acc[7], g1.w));
        }
    }
}

// ============================== launch =====================================

extern "C" void kernel_launch(void* const* d_in, const int* in_sizes, int n_in,
                              void* d_out, int out_size, void* d_ws, size_t ws_size,
                              hipStream_t stream) {
    const float* q    = (const float*)d_in[0];
    const float* p    = (const float*)d_in[1];
    const float* M    = (const float*)d_in[2];
    const int*   src  = (const int*)d_in[3];
    const int*   dst  = (const int*)d_in[4];
    const float* W1   = (const float*)d_in[5];
    const float* b1   = (const float*)d_in[6];
    const float* W2   = (const float*)d_in[7];
    const float* b2   = (const float*)d_in[8];
    const float* grav = (const float*)d_in[9];
    float* out = (float*)d_out;

    int N = in_sizes[0] / DD;
    int E = in_sizes[3];
    size_t n = (size_t)N;
    int NB = (N + 511) >> 9;
    int NC = (E + CH - 1) / CH;

    // ---- data region (46N 4-byte words) ----
    float*   ws   = (float*)d_ws;
    float*   a_   = ws;             // N
    float*   b_   = ws + n;         // N
    float*   qn   = ws + 2  * n;    // 8N f32 (reused as gq2 after phase G)
    float*   agg1 = ws + 10 * n;    // 8N f32 (live through bwd)
    float*   gh   = ws + 18 * n;    // 8N f32
    __half2* hm   = (__half2*)(ws + 26 * n);  // 8N half2 (8N words)
    __half*  ya   = (__half*)(ws + 34 * n);   // 8N half (4N words)
    __half*  bgh  = (__half*)(ws + 38 * n);   // 8N half (4N words)
    __half*  gz1b = (__half*)(ws + 42 * n);   // 8N half (4N words)
    float*   gq2  = qn;

    // ---- int region ----
    int* iw        = (int*)(ws + 46 * n);
    int* csr_in    = iw;                       // E
    int* csr_out   = iw + (size_t)E;           // E
    int* start_in  = iw + 2 * (size_t)E;       // N+1
    int* start_out = start_in + n + 1;         // N+1
    int* gHistIn   = start_out + n + 1;        // 256
    int* gHistOut  = gHistIn + 256;            // 256
    int* cStartIn  = gHistOut + 256;           // NB+1
    int* cStartOut = cStartIn + NB + 1;        // NB+1
    int* cCurIn    = cStartOut + NB + 1;       // NB
    int* cCurOut   = cCurIn + NB;              // NB
    int* iwEnd     = cCurOut + NB;
    float* W12p    = (float*)iwEnd;            // HH*WPITCH = 5120 floats
    int* intAfter  = (int*)(W12p + HH * WPITCH);
    // partition scratch: both dirs alias the data region (dead during build)
    int* P_in  = (E <= 16 * (long long)n) ? (int*)ws            : intAfter;
    int* P_out = (E <= 16 * (long long)n) ? (int*)(ws + 16 * n) : intAfter + E;
    int* barp  = (E <= 16 * (long long)n) ? intAfter            : intAfter + 2 * (size_t)E;

    Params prm;
    prm.q = q; prm.p = p; prm.M = M;
    prm.W1 = W1; prm.b1w = b1; prm.W2 = W2; prm.b2w = b2; prm.grav = grav;
    prm.src = src; prm.dst = dst;
    prm.out = out;
    prm.a = a_; prm.bn = b_; prm.qn = qn; prm.agg1 = agg1; prm.gh = gh;
    prm.W12p = W12p;
    prm.hm = hm; prm.ya = ya; prm.bgh = bgh; prm.gz1b = gz1b; prm.gq2 = gq2;
    prm.csr_in = csr_in; prm.csr_out = csr_out;
    prm.start_in = start_in; prm.start_out = start_out;
    prm.gHistIn = gHistIn; prm.gHistOut = gHistOut;
    prm.cStartIn = cStartIn; prm.cStartOut = cStartOut;
    prm.cCurIn = cCurIn; prm.cCurOut = cCurOut;
    prm.P_in = P_in; prm.P_out = P_out;
    prm.bar = barp;
    prm.N = N; prm.E = E; prm.NB = NB; prm.NC = NC;

    // zero the global hists (512 ints) and the barrier state (SL_TOTAL ints)
    hipMemsetAsync(gHistIn, 0, 512 * sizeof(int), stream);
    hipMemsetAsync(barp, 0, SL_TOTAL * sizeof(int), stream);

    mega<<<dim3(NBLK), dim3(256), 0, stream>>>(prm);
}